// Round 12
// baseline (390.007 us; speedup 1.0000x reference)
//
#include <hip/hip_runtime.h>
#include <math.h>

#define BATCH 2
#define SEQ   4096
#define DIN   256
#define NH    8
#define DH    32            // head dim (dk = dv = 32)
#define BH    (BATCH*NH)    // 16
#define NSPLIT 8            // key-split factor
#define KRANGE (SEQ/NSPLIT) // 512 keys per block
#define TILES  (KRANGE/64)  // 8 tiles of 64 keys
#define QBLK   512          // q rows per block; 64 per wave (4 subtiles of 16)

typedef short bf16x8 __attribute__((ext_vector_type(8)));
typedef float f32x4  __attribute__((ext_vector_type(4)));

// raw v_exp_f32 (base-2). Scores bounded -> no denorm fixup needed.
#if defined(__has_builtin)
#if __has_builtin(__builtin_amdgcn_exp2f)
#define EXP2(x) __builtin_amdgcn_exp2f(x)
#else
#define EXP2_ASM 1
#endif
#else
#define EXP2_ASM 1
#endif
#ifdef EXP2_ASM
__device__ __forceinline__ float exp2_raw(float x) {
    float r;
    asm("v_exp_f32 %0, %1\n\ts_nop 1" : "=v"(r) : "v"(x));
    return r;
}
#define EXP2(x) exp2_raw(x)
#endif

#define SC2 0.25508218f     // log2(e)/sqrt(32) — folded into Q at projection

__device__ __forceinline__ unsigned short f2bf(float f) {
    unsigned int u = __builtin_bit_cast(unsigned int, f);
    u += 0x7fffu + ((u >> 16) & 1u);
    return (unsigned short)(u >> 16);
}

// pack 2 rounded bf16 (round-half-up), one v_perm + 2 adds
__device__ __forceinline__ unsigned int pack_bf2(float f0, float f1) {
    unsigned int u0 = __builtin_bit_cast(unsigned int, f0) + 0x8000u;
    unsigned int u1 = __builtin_bit_cast(unsigned int, f1) + 0x8000u;
    return __builtin_amdgcn_perm(u1, u0, 0x07060302u);
}

// pack 2 TRUNCATED bf16, single v_perm (hot attn loop). Truncation bias
// cancels exactly in softmax: l is computed from the same truncated P.
__device__ __forceinline__ unsigned int pack_bf2_t(float f0, float f1) {
    return __builtin_amdgcn_perm(__builtin_bit_cast(unsigned int, f1),
                                 __builtin_bit_cast(unsigned int, f0),
                                 0x07060302u);
}

#if defined(__has_builtin)
#if __has_builtin(__builtin_amdgcn_global_load_lds)
#define HAS_ASYNC_LDS 1
#endif
#endif

// async global->LDS, 16B/lane: wave-uniform LDS base, HW scatters lane i to
// base + i*16 (verified R5-R11).
__device__ __forceinline__ void stage16(const unsigned short* g,
                                        unsigned short* lds_base, int lane) {
#ifdef HAS_ASYNC_LDS
    __builtin_amdgcn_global_load_lds(
        (const __attribute__((address_space(1))) unsigned int*)g,
        (__attribute__((address_space(3))) unsigned int*)lds_base, 16, 0, 0);
#else
    *(bf16x8*)(lds_base + (size_t)lane * 8) = *(const bf16x8*)g;
#endif
}

// ---------------- prep: W -> Wt[t][k] bf16 (48 blocks) ----------------
__global__ __launch_bounds__(256) void prep_kernel(
    const float* __restrict__ Wq, const float* __restrict__ Wk, const float* __restrict__ Wv,
    unsigned short* __restrict__ Wt)
{
    __shared__ float ws[64][65];
    const int t = threadIdx.x;
    int wsel = blockIdx.x >> 4;
    int tile = blockIdx.x & 15;
    int tr = (tile >> 2) * 64;
    int tc = (tile & 3) * 64;
    const float* __restrict__ W = (wsel == 0) ? Wq : (wsel == 1) ? Wk : Wv;
    #pragma unroll
    for (int i = 0; i < 16; i++) {
        int row = i * 4 + (t >> 6), col = t & 63;
        ws[row][col] = W[(size_t)(tr + row) * DIN + tc + col];
    }
    __syncthreads();
    unsigned short* dst = Wt + (size_t)wsel * DIN * DIN;
    #pragma unroll
    for (int i = 0; i < 16; i++) {
        int orow = i * 4 + (t >> 6), ocol = t & 63;
        dst[(size_t)(tc + orow) * DIN + tr + ocol] = f2bf(ws[ocol][orow]);
    }
}

// ---------------- proj (R8-proven): x staged fp32->bf16 in-kernel ----------
__global__ __launch_bounds__(256) void proj_kernel(
    const float* __restrict__ x, const unsigned short* __restrict__ Wt,
    unsigned short* __restrict__ qh, unsigned short* __restrict__ kh,
    unsigned short* __restrict__ vt)
{
    __shared__ __align__(16) unsigned short abuf[8][4][64][8];  // 32 KiB
    __shared__ __align__(16) unsigned short bbuf[8][4][64][8];  // 32 KiB

    const int wsel = blockIdx.y;
    const int w    = threadIdx.x >> 6;
    const int lane = threadIdx.x & 63;
    const int quad = lane >> 4;
    const int l16  = lane & 15;

    const int sl   = lane ^ (lane >> 3);      // producer: lane -> slot
    const int sl16 = sl >> 2, squad = sl & 3;
    const int s_ = (l16 << 2) | quad;         // consumer slot for (l16, quad)
    const int jj = (s_ & 56) | ((s_ ^ (s_ >> 3)) & 7);

    int arow0, brow0;
    const unsigned short* Wbase;
    const float* Xbase;
    unsigned short (*wdst)[4][64][8];
    unsigned short (*xdst)[4][64][8];
    if (wsel < 2) {
        int tt = blockIdx.x >> 7, nt = blockIdx.x & 127;
        arow0 = tt * 64; brow0 = nt * 64;
        Wbase = Wt + (size_t)wsel * DIN * DIN + (size_t)arow0 * DIN;
        Xbase = x + (size_t)brow0 * DIN;
        wdst = abuf; xdst = bbuf;
    } else {
        int nt = blockIdx.x >> 2, tt = blockIdx.x & 3;
        arow0 = nt * 64; brow0 = tt * 64;
        Xbase = x + (size_t)arow0 * DIN;
        Wbase = Wt + (size_t)2 * DIN * DIN + (size_t)brow0 * DIN;
        wdst = bbuf; xdst = abuf;
    }

    #pragma unroll
    for (int i = 0; i < 8; i++) {
        int id = w * 8 + i;
        int kb = id >> 2, rt = id & 3;
        stage16(Wbase + (size_t)(rt * 16 + sl16) * DIN + kb * 32 + squad * 8,
                &wdst[kb][rt][0][0], lane);
    }
    #pragma unroll
    for (int i = 0; i < 8; i++) {
        int id = w * 8 + i;
        int kb = id >> 2, rt = id & 3;
        const float4* src = (const float4*)(Xbase + (size_t)(rt * 16 + sl16) * DIN
                                            + kb * 32 + squad * 8);
        float4 a = src[0], b = src[1];
        uint4 p = { pack_bf2(a.x, a.y), pack_bf2(a.z, a.w),
                    pack_bf2(b.x, b.y), pack_bf2(b.z, b.w) };
        *(uint4*)(&xdst[kb][rt][0][0] + (size_t)lane * 8) = p;
    }
    __syncthreads();

    f32x4 acc[4];
    #pragma unroll
    for (int c = 0; c < 4; c++) acc[c] = (f32x4){0.f, 0.f, 0.f, 0.f};
    #pragma unroll
    for (int kb = 0; kb < 8; kb++) {
        bf16x8 af = *(const bf16x8*)&abuf[kb][w][jj][0];
        #pragma unroll
        for (int c = 0; c < 4; c++) {
            bf16x8 bfr = *(const bf16x8*)&bbuf[kb][c][jj][0];
            acc[c] = __builtin_amdgcn_mfma_f32_16x16x32_bf16(af, bfr, acc[c], 0, 0, 0);
        }
    }

    if (wsel < 2) {
        const float scl = (wsel == 0) ? SC2 : 1.0f;
        unsigned short* __restrict__ dst0 = (wsel == 0) ? qh : kh;
        const int t0 = arow0 + w * 16;
        const int h = t0 >> 5, d0 = (t0 & 31) + quad * 4;
        #pragma unroll
        for (int c = 0; c < 4; c++) {
            int n = brow0 + c * 16 + l16;
            int b = n >> 12, n12 = n & 4095;
            unsigned int u01 = pack_bf2(acc[c][0] * scl, acc[c][1] * scl);
            unsigned int u23 = pack_bf2(acc[c][2] * scl, acc[c][3] * scl);
            *(uint2*)&dst0[((size_t)(b * NH + h) * SEQ + n12) * DH + d0] = make_uint2(u01, u23);
        }
    } else {
        const int n0w = arow0 + w * 16;
        const int b = n0w >> 12, nbase = (n0w & 4095) + quad * 4;
        #pragma unroll
        for (int c = 0; c < 4; c++) {
            int t = brow0 + c * 16;
            int h = t >> 5, d = (t & 31) + l16;
            unsigned int u01 = pack_bf2(acc[c][0], acc[c][1]);
            unsigned int u23 = pack_bf2(acc[c][2], acc[c][3]);
            *(uint2*)&vt[((size_t)(b * NH + h) * DH + d) * SEQ + nbase] = make_uint2(u01, u23);
        }
    }
}

// ---------------- Flash attention v12: 8-wave blocks, max occupancy ----------
// Block = 512 q (64/wave, 8 waves) x 512 keys. One shared 64-key K/V tile per
// iter staged by 1 lds-dma per wave (waves 0-3: K chunks, 4-7: V chunks).
// LDS 32 KiB -> 4 blocks/CU x 8 waves = 32 waves/CU (8/SIMD, HW max).
// __launch_bounds__(512,8) caps VGPR at 64 (compiler's choice for 3 rounds).
__global__ __launch_bounds__(512, 8) void attn_kernel(
    const unsigned short* __restrict__ qh,
    const unsigned short* __restrict__ kh,
    const unsigned short* __restrict__ vt,
    unsigned short* __restrict__ po, float* __restrict__ pl)
{
    __shared__ __align__(16) unsigned short pbuf[8][16][64];     // 16 KiB
    __shared__ __align__(16) unsigned short kbuf[2][4][64][8];   // 8 KiB
    __shared__ __align__(16) unsigned short vbuf[2][4][64][8];   // 8 KiB

    const int tid  = threadIdx.x;
    const int wave = tid >> 6;        // 0..7
    const int lane = tid & 63;
    const int quad = lane >> 4;
    const int l16  = lane & 15;
    const int sw   = l16 & 7;         // pbuf XOR swizzle key

    const int bh = blockIdx.x & 15;   // head -> XCD pinning
    const int qb = (blockIdx.x >> 4) & 7;
    const int ks = blockIdx.x >> 7;   // key-split 0..7
    const int q0 = qb * QBLK + wave * 64;
    const int kbase = ks * KRANGE;

    const unsigned short* __restrict__ Qp = qh + (size_t)bh * SEQ * DH;
    const unsigned short* __restrict__ Kp = kh + (size_t)bh * SEQ * DH;
    const unsigned short* __restrict__ Vp = vt + (size_t)bh * DH * SEQ;

    const int sl    = lane ^ (lane >> 3);
    const int sl16  = sl >> 2, squad = sl & 3;
    // staging: wave w<4 stages K chunk w; w>=4 stages V chunk w-4
    const int iskv = wave >> 2;             // 0 = K, 1 = V
    const int ch   = wave & 3;
    const unsigned short* src0;
    unsigned short* dst_lo;
    unsigned short* dst_hi;
    if (!iskv) {
        src0   = Kp + (size_t)(kbase + ch * 16 + sl16) * DH + squad * 8;
        dst_lo = &kbuf[0][ch][0][0];
        dst_hi = &kbuf[1][ch][0][0];
    } else {
        int vdh = ch >> 1, vkh = ch & 1;
        src0   = Vp + (size_t)(vdh * 16 + sl16) * SEQ + kbase + vkh * 32 + squad * 8;
        dst_lo = &vbuf[0][ch][0][0];
        dst_hi = &vbuf[1][ch][0][0];
    }
    const int sstep = iskv ? 64 : 64 * DH;  // per-tile source advance (elements)

    const int s_ = (l16 << 2) | quad;
    const int jj = (s_ & 56) | ((s_ ^ (s_ >> 3)) & 7);

    bf16x8 qf[4];
    #pragma unroll
    for (int i = 0; i < 4; i++)
        qf[i] = *(const bf16x8*)(Qp + (size_t)(q0 + i * 16 + l16) * DH + quad * 8);

    const bf16x8 ones = {0x3F80, 0x3F80, 0x3F80, 0x3F80,
                         0x3F80, 0x3F80, 0x3F80, 0x3F80};

    f32x4 o[4][2];
    f32x4 lones[4];
    #pragma unroll
    for (int i = 0; i < 4; i++) {
        o[i][0] = (f32x4){0.f, 0.f, 0.f, 0.f};
        o[i][1] = (f32x4){0.f, 0.f, 0.f, 0.f};
        lones[i] = (f32x4){0.f, 0.f, 0.f, 0.f};
    }
    const f32x4 z = {0.f, 0.f, 0.f, 0.f};

    stage16(src0, dst_lo, lane);
    src0 += sstep;

    for (int t = 0; t < TILES; t++) {
        const int buf = t & 1;

        __syncthreads();   // tile t staged; buf^1 free

        if (t + 1 < TILES) {
            stage16(src0, buf ? dst_lo : dst_hi, lane);
            src0 += sstep;
        }

        // read shared K/V fragments ONCE per wave, reuse across 4 q-subtiles
        bf16x8 kf[4], vf[4];
        #pragma unroll
        for (int c = 0; c < 4; c++) kf[c] = *(const bf16x8*)&kbuf[buf][c][jj][0];
        #pragma unroll
        for (int f = 0; f < 4; f++) vf[f] = *(const bf16x8*)&vbuf[buf][f][jj][0];

        #pragma unroll
        for (int qt = 0; qt < 4; qt++) {
            #pragma unroll
            for (int c = 0; c < 4; c++) {
                f32x4 s = __builtin_amdgcn_mfma_f32_16x16x32_bf16(kf[c], qf[qt], z, 0, 0, 0);
                float e0 = EXP2(s[0]);
                float e1 = EXP2(s[1]);
                float e2 = EXP2(s[2]);
                float e3 = EXP2(s[3]);
                int chs = ((c * 2 + (quad >> 1)) ^ sw) * 8 + (quad & 1) * 4;
                *(uint2*)&pbuf[wave][l16][chs] =
                    make_uint2(pack_bf2_t(e0, e1), pack_bf2_t(e2, e3));
            }
            bf16x8 pf0 = *(const bf16x8*)&pbuf[wave][l16][((0 + quad) ^ sw) * 8];
            bf16x8 pf1 = *(const bf16x8*)&pbuf[wave][l16][((4 + quad) ^ sw) * 8];
            o[qt][0] = __builtin_amdgcn_mfma_f32_16x16x32_bf16(pf0, vf[0], o[qt][0], 0, 0, 0);
            o[qt][0] = __builtin_amdgcn_mfma_f32_16x16x32_bf16(pf1, vf[1], o[qt][0], 0, 0, 0);
            o[qt][1] = __builtin_amdgcn_mfma_f32_16x16x32_bf16(pf0, vf[2], o[qt][1], 0, 0, 0);
            o[qt][1] = __builtin_amdgcn_mfma_f32_16x16x32_bf16(pf1, vf[3], o[qt][1], 0, 0, 0);
            lones[qt] = __builtin_amdgcn_mfma_f32_16x16x32_bf16(pf0, ones, lones[qt], 0, 0, 0);
            lones[qt] = __builtin_amdgcn_mfma_f32_16x16x32_bf16(pf1, ones, lones[qt], 0, 0, 0);
        }
    }

    // epilogue: bf16 partial O + fp32 partial l (lones rows align with o rows)
    const size_t obase = (size_t)(ks * BH + bh) * SEQ;
    #pragma unroll
    for (int qt = 0; qt < 4; qt++) {
        if (l16 == 0) {
            #pragma unroll
            for (int r = 0; r < 4; r++)
                pl[obase + q0 + qt * 16 + quad * 4 + r] = lones[qt][r];
        }
        #pragma unroll
        for (int r = 0; r < 4; r++) {
            int n = q0 + qt * 16 + quad * 4 + r;
            unsigned short* dst = po + (obase + n) * DH;
            dst[l16]      = f2bf(o[qt][0][r]);
            dst[16 + l16] = f2bf(o[qt][1][r]);
        }
    }
}

// ---------------- merge: sum bf16 split partials, divide, write out ---------
__global__ __launch_bounds__(256) void merge_kernel(
    const unsigned short* __restrict__ po, const float* __restrict__ pl,
    float* __restrict__ out)
{
    int t    = blockIdx.x * 256 + threadIdx.x;   // 0 .. 512K-1
    int d8   = t & 7;
    int pair = t >> 3;
    int bh   = pair >> 12;
    int n    = pair & 4095;
    float s0 = 0.f, s1 = 0.f, s2 = 0.f, s3 = 0.f, ls = 0.f;
    #pragma unroll
    for (int sp = 0; sp < NSPLIT; sp++) {
        size_t base = (size_t)(sp * BH + bh) * SEQ + n;
        uint2 v = ((const uint2*)(po + base * DH))[d8];
        s0 += __builtin_bit_cast(float, v.x << 16);
        s1 += __builtin_bit_cast(float, v.x & 0xFFFF0000u);
        s2 += __builtin_bit_cast(float, v.y << 16);
        s3 += __builtin_bit_cast(float, v.y & 0xFFFF0000u);
        ls += pl[base];
    }
    float inv = 1.f / ls;
    int b = bh >> 3, h = bh & 7;
    float4 o = {s0 * inv, s1 * inv, s2 * inv, s3 * inv};
    ((float4*)(out + ((size_t)b * SEQ + n) * (NH * DH) + h * DH))[d8] = o;
}

extern "C" void kernel_launch(void* const* d_in, const int* in_sizes, int n_in,
                              void* d_out, int out_size, void* d_ws, size_t ws_size,
                              hipStream_t stream)
{
    const float* x  = (const float*)d_in[0];
    const float* Wq = (const float*)d_in[1];
    const float* Wk = (const float*)d_in[2];
    const float* Wv = (const float*)d_in[3];
    float* out = (float*)d_out;

    // ws: qh|kh|vt (4 MiB each) | Wt (384 KiB) | po (32 MiB bf16) | pl (2 MiB f32)
    unsigned short* qh = (unsigned short*)d_ws;
    unsigned short* kh = qh + (size_t)BH * SEQ * DH;
    unsigned short* vt = kh + (size_t)BH * SEQ * DH;
    unsigned short* Wt = vt + (size_t)BH * SEQ * DH;
    unsigned short* po = Wt + 3 * DIN * DIN;
    float* pl = (float*)(po + (size_t)NSPLIT * BH * SEQ * DH);

    prep_kernel<<<dim3(48), 256, 0, stream>>>(Wq, Wk, Wv, Wt);
    proj_kernel<<<dim3(512, 3), 256, 0, stream>>>(x, Wt, qh, kh, vt);
    attn_kernel<<<dim3(BH * (SEQ / QBLK) * NSPLIT), 512, 0, stream>>>(qh, kh, vt, po, pl);
    merge_kernel<<<dim3(2048), 256, 0, stream>>>(po, pl, out);
}

// Round 13
// 205.875 us; speedup vs baseline: 1.8944x; 1.8944x over previous
//
#include <hip/hip_runtime.h>
#include <math.h>

#define BATCH 2
#define SEQ   4096
#define DIN   256
#define NH    8
#define DH    32            // head dim (dk = dv = 32)
#define BH    (BATCH*NH)    // 16
#define NSPLIT 8            // key-split factor
#define KRANGE (SEQ/NSPLIT) // 512 keys per block
#define TILES  (KRANGE/64)  // 8 tiles of 64 keys
#define QTILE  256          // q rows per block; 64 per wave (4 subtiles of 16)

typedef short bf16x8 __attribute__((ext_vector_type(8)));
typedef float f32x4  __attribute__((ext_vector_type(4)));

// raw v_exp_f32 (base-2). Scores bounded -> no denorm fixup needed.
#if defined(__has_builtin)
#if __has_builtin(__builtin_amdgcn_exp2f)
#define EXP2(x) __builtin_amdgcn_exp2f(x)
#else
#define EXP2_ASM 1
#endif
#else
#define EXP2_ASM 1
#endif

// batch of 4 independent exp2: one trailing s_nop covers the trans-use hazard
// (vs one s_nop per exp in R7-R12 -> ~96 fewer wasted issue cycles/wave-iter)
__device__ __forceinline__ void exp4(float& a, float& b, float& c, float& d) {
#ifdef EXP2_ASM
    float r0, r1, r2, r3;
    asm("v_exp_f32 %0, %4\n\t"
        "v_exp_f32 %1, %5\n\t"
        "v_exp_f32 %2, %6\n\t"
        "v_exp_f32 %3, %7\n\t"
        "s_nop 1"
        : "=&v"(r0), "=&v"(r1), "=&v"(r2), "=&v"(r3)
        : "v"(a), "v"(b), "v"(c), "v"(d));
    a = r0; b = r1; c = r2; d = r3;
#else
    a = EXP2(a); b = EXP2(b); c = EXP2(c); d = EXP2(d);
#endif
}

#define SC2 0.25508218f     // log2(e)/sqrt(32) — folded into Q at projection

__device__ __forceinline__ unsigned short f2bf(float f) {
    unsigned int u = __builtin_bit_cast(unsigned int, f);
    u += 0x7fffu + ((u >> 16) & 1u);
    return (unsigned short)(u >> 16);
}

// pack 2 rounded bf16 (round-half-up), one v_perm + 2 adds
__device__ __forceinline__ unsigned int pack_bf2(float f0, float f1) {
    unsigned int u0 = __builtin_bit_cast(unsigned int, f0) + 0x8000u;
    unsigned int u1 = __builtin_bit_cast(unsigned int, f1) + 0x8000u;
    return __builtin_amdgcn_perm(u1, u0, 0x07060302u);
}

// pack 2 TRUNCATED bf16, single v_perm (hot attn loop). Truncation bias
// cancels exactly in softmax: l is computed from the same truncated P.
__device__ __forceinline__ unsigned int pack_bf2_t(float f0, float f1) {
    return __builtin_amdgcn_perm(__builtin_bit_cast(unsigned int, f1),
                                 __builtin_bit_cast(unsigned int, f0),
                                 0x07060302u);
}

#if defined(__has_builtin)
#if __has_builtin(__builtin_amdgcn_global_load_lds)
#define HAS_ASYNC_LDS 1
#endif
#endif

// async global->LDS, 16B/lane: wave-uniform LDS base, HW scatters lane i to
// base + i*16 (verified R5-R12).
__device__ __forceinline__ void stage16(const unsigned short* g,
                                        unsigned short* lds_base, int lane) {
#ifdef HAS_ASYNC_LDS
    __builtin_amdgcn_global_load_lds(
        (const __attribute__((address_space(1))) unsigned int*)g,
        (__attribute__((address_space(3))) unsigned int*)lds_base, 16, 0, 0);
#else
    *(bf16x8*)(lds_base + (size_t)lane * 8) = *(const bf16x8*)g;
#endif
}

// ---------------- prep: W -> Wt[t][k] bf16 (48 blocks) ----------------
__global__ __launch_bounds__(256) void prep_kernel(
    const float* __restrict__ Wq, const float* __restrict__ Wk, const float* __restrict__ Wv,
    unsigned short* __restrict__ Wt)
{
    __shared__ float ws[64][65];
    const int t = threadIdx.x;
    int wsel = blockIdx.x >> 4;
    int tile = blockIdx.x & 15;
    int tr = (tile >> 2) * 64;
    int tc = (tile & 3) * 64;
    const float* __restrict__ W = (wsel == 0) ? Wq : (wsel == 1) ? Wk : Wv;
    #pragma unroll
    for (int i = 0; i < 16; i++) {
        int row = i * 4 + (t >> 6), col = t & 63;
        ws[row][col] = W[(size_t)(tr + row) * DIN + tc + col];
    }
    __syncthreads();
    unsigned short* dst = Wt + (size_t)wsel * DIN * DIN;
    #pragma unroll
    for (int i = 0; i < 16; i++) {
        int orow = i * 4 + (t >> 6), ocol = t & 63;
        dst[(size_t)(tc + orow) * DIN + tr + ocol] = f2bf(ws[ocol][orow]);
    }
}

// ---------------- proj (R8-proven): x staged fp32->bf16 in-kernel ----------
__global__ __launch_bounds__(256) void proj_kernel(
    const float* __restrict__ x, const unsigned short* __restrict__ Wt,
    unsigned short* __restrict__ qh, unsigned short* __restrict__ kh,
    unsigned short* __restrict__ vt)
{
    __shared__ __align__(16) unsigned short abuf[8][4][64][8];  // 32 KiB
    __shared__ __align__(16) unsigned short bbuf[8][4][64][8];  // 32 KiB

    const int wsel = blockIdx.y;
    const int w    = threadIdx.x >> 6;
    const int lane = threadIdx.x & 63;
    const int quad = lane >> 4;
    const int l16  = lane & 15;

    const int sl   = lane ^ (lane >> 3);      // producer: lane -> slot
    const int sl16 = sl >> 2, squad = sl & 3;
    const int s_ = (l16 << 2) | quad;         // consumer slot for (l16, quad)
    const int jj = (s_ & 56) | ((s_ ^ (s_ >> 3)) & 7);

    int arow0, brow0;
    const unsigned short* Wbase;
    const float* Xbase;
    unsigned short (*wdst)[4][64][8];
    unsigned short (*xdst)[4][64][8];
    if (wsel < 2) {
        int tt = blockIdx.x >> 7, nt = blockIdx.x & 127;
        arow0 = tt * 64; brow0 = nt * 64;
        Wbase = Wt + (size_t)wsel * DIN * DIN + (size_t)arow0 * DIN;
        Xbase = x + (size_t)brow0 * DIN;
        wdst = abuf; xdst = bbuf;
    } else {
        int nt = blockIdx.x >> 2, tt = blockIdx.x & 3;
        arow0 = nt * 64; brow0 = tt * 64;
        Xbase = x + (size_t)arow0 * DIN;
        Wbase = Wt + (size_t)2 * DIN * DIN + (size_t)brow0 * DIN;
        wdst = bbuf; xdst = abuf;
    }

    #pragma unroll
    for (int i = 0; i < 8; i++) {
        int id = w * 8 + i;
        int kb = id >> 2, rt = id & 3;
        stage16(Wbase + (size_t)(rt * 16 + sl16) * DIN + kb * 32 + squad * 8,
                &wdst[kb][rt][0][0], lane);
    }
    #pragma unroll
    for (int i = 0; i < 8; i++) {
        int id = w * 8 + i;
        int kb = id >> 2, rt = id & 3;
        const float4* src = (const float4*)(Xbase + (size_t)(rt * 16 + sl16) * DIN
                                            + kb * 32 + squad * 8);
        float4 a = src[0], b = src[1];
        uint4 p = { pack_bf2(a.x, a.y), pack_bf2(a.z, a.w),
                    pack_bf2(b.x, b.y), pack_bf2(b.z, b.w) };
        *(uint4*)(&xdst[kb][rt][0][0] + (size_t)lane * 8) = p;
    }
    __syncthreads();

    f32x4 acc[4];
    #pragma unroll
    for (int c = 0; c < 4; c++) acc[c] = (f32x4){0.f, 0.f, 0.f, 0.f};
    #pragma unroll
    for (int kb = 0; kb < 8; kb++) {
        bf16x8 af = *(const bf16x8*)&abuf[kb][w][jj][0];
        #pragma unroll
        for (int c = 0; c < 4; c++) {
            bf16x8 bfr = *(const bf16x8*)&bbuf[kb][c][jj][0];
            acc[c] = __builtin_amdgcn_mfma_f32_16x16x32_bf16(af, bfr, acc[c], 0, 0, 0);
        }
    }

    if (wsel < 2) {
        const float scl = (wsel == 0) ? SC2 : 1.0f;
        unsigned short* __restrict__ dst0 = (wsel == 0) ? qh : kh;
        const int t0 = arow0 + w * 16;
        const int h = t0 >> 5, d0 = (t0 & 31) + quad * 4;
        #pragma unroll
        for (int c = 0; c < 4; c++) {
            int n = brow0 + c * 16 + l16;
            int b = n >> 12, n12 = n & 4095;
            unsigned int u01 = pack_bf2(acc[c][0] * scl, acc[c][1] * scl);
            unsigned int u23 = pack_bf2(acc[c][2] * scl, acc[c][3] * scl);
            *(uint2*)&dst0[((size_t)(b * NH + h) * SEQ + n12) * DH + d0] = make_uint2(u01, u23);
        }
    } else {
        const int n0w = arow0 + w * 16;
        const int b = n0w >> 12, nbase = (n0w & 4095) + quad * 4;
        #pragma unroll
        for (int c = 0; c < 4; c++) {
            int t = brow0 + c * 16;
            int h = t >> 5, d = (t & 31) + l16;
            unsigned int u01 = pack_bf2(acc[c][0], acc[c][1]);
            unsigned int u23 = pack_bf2(acc[c][2], acc[c][3]);
            *(uint2*)&vt[((size_t)(b * NH + h) * DH + d) * SEQ + nbase] = make_uint2(u01, u23);
        }
    }
}

// ---------------- Flash attention v13: R11 structure at 5 blocks/CU ---------
// Block = 256 q (64/wave, 4 waves) x 512 keys (NSPLIT=8, grid 2048).
// LDS 32 KiB -> 5 blocks/CU resident (20 waves/CU, +25% vs R11's 4).
// launch_bounds(256,5): VGPR cap ~102 >= the 64 this kernel needs (no R12 spill).
__global__ __launch_bounds__(256, 5) void attn_kernel(
    const unsigned short* __restrict__ qh,
    const unsigned short* __restrict__ kh,
    const unsigned short* __restrict__ vt,
    unsigned short* __restrict__ po, float* __restrict__ pl)
{
    __shared__ __align__(16) unsigned short pbuf[4][2][16][64];  // 16 KiB
    __shared__ __align__(16) unsigned short kbuf[2][4][64][8];   // 8 KiB
    __shared__ __align__(16) unsigned short vbuf[2][4][64][8];   // 8 KiB

    const int tid  = threadIdx.x;
    const int wave = tid >> 6;
    const int lane = tid & 63;
    const int quad = lane >> 4;
    const int l16  = lane & 15;
    const int sw   = l16 & 7;         // pbuf XOR swizzle key

    const int bh = blockIdx.x & 15;   // head -> XCD pinning
    const int qb = (blockIdx.x >> 4) & 15;
    const int ks = blockIdx.x >> 8;   // key-split 0..7
    const int q0 = qb * QTILE + wave * 64;
    const int kbase = ks * KRANGE;

    const unsigned short* __restrict__ Qp = qh + (size_t)bh * SEQ * DH;
    const unsigned short* __restrict__ Kp = kh + (size_t)bh * SEQ * DH;
    const unsigned short* __restrict__ Vp = vt + (size_t)bh * DH * SEQ;

    const int sl    = lane ^ (lane >> 3);
    const int sl16  = sl >> 2, squad = sl & 3;
    const unsigned short* ksrc = Kp + (size_t)(kbase + wave * 16 + sl16) * DH + squad * 8;
    const int vdh = wave >> 1, vkh = wave & 1;
    const unsigned short* vsrc = Vp + (size_t)(vdh * 16 + sl16) * SEQ + kbase + vkh * 32 + squad * 8;

    const int s_ = (l16 << 2) | quad;
    const int jj = (s_ & 56) | ((s_ ^ (s_ >> 3)) & 7);

    bf16x8 qf[4];
    #pragma unroll
    for (int i = 0; i < 4; i++)
        qf[i] = *(const bf16x8*)(Qp + (size_t)(q0 + i * 16 + l16) * DH + quad * 8);

    const bf16x8 ones = {0x3F80, 0x3F80, 0x3F80, 0x3F80,
                         0x3F80, 0x3F80, 0x3F80, 0x3F80};

    f32x4 o[4][2];
    f32x4 lones[4];
    #pragma unroll
    for (int i = 0; i < 4; i++) {
        o[i][0] = (f32x4){0.f, 0.f, 0.f, 0.f};
        o[i][1] = (f32x4){0.f, 0.f, 0.f, 0.f};
        lones[i] = (f32x4){0.f, 0.f, 0.f, 0.f};
    }
    const f32x4 z = {0.f, 0.f, 0.f, 0.f};

    stage16(ksrc, &kbuf[0][wave][0][0], lane);
    stage16(vsrc, &vbuf[0][wave][0][0], lane);
    ksrc += 64 * DH;
    vsrc += 64;

    for (int t = 0; t < TILES; t++) {
        const int buf = t & 1;

        __syncthreads();   // tile t staged; buf^1 free

        if (t + 1 < TILES) {
            stage16(ksrc, &kbuf[buf ^ 1][wave][0][0], lane);
            stage16(vsrc, &vbuf[buf ^ 1][wave][0][0], lane);
            ksrc += 64 * DH;
            vsrc += 64;
        }

        // read shared K/V fragments ONCE per wave, reuse across 4 q-subtiles
        bf16x8 kf[4], vf[4];
        #pragma unroll
        for (int c = 0; c < 4; c++) kf[c] = *(const bf16x8*)&kbuf[buf][c][jj][0];
        #pragma unroll
        for (int f = 0; f < 4; f++) vf[f] = *(const bf16x8*)&vbuf[buf][f][jj][0];

        #pragma unroll
        for (int qt = 0; qt < 4; qt++) {
            const int pr = qt & 1;    // pbuf parity region
            #pragma unroll
            for (int c = 0; c < 4; c++) {
                f32x4 s = __builtin_amdgcn_mfma_f32_16x16x32_bf16(kf[c], qf[qt], z, 0, 0, 0);
                float e0 = s[0], e1 = s[1], e2 = s[2], e3 = s[3];
                exp4(e0, e1, e2, e3);
                int chs = ((c * 2 + (quad >> 1)) ^ sw) * 8 + (quad & 1) * 4;
                *(uint2*)&pbuf[wave][pr][l16][chs] =
                    make_uint2(pack_bf2_t(e0, e1), pack_bf2_t(e2, e3));
            }
            bf16x8 pf0 = *(const bf16x8*)&pbuf[wave][pr][l16][((0 + quad) ^ sw) * 8];
            bf16x8 pf1 = *(const bf16x8*)&pbuf[wave][pr][l16][((4 + quad) ^ sw) * 8];
            o[qt][0] = __builtin_amdgcn_mfma_f32_16x16x32_bf16(pf0, vf[0], o[qt][0], 0, 0, 0);
            o[qt][0] = __builtin_amdgcn_mfma_f32_16x16x32_bf16(pf1, vf[1], o[qt][0], 0, 0, 0);
            o[qt][1] = __builtin_amdgcn_mfma_f32_16x16x32_bf16(pf0, vf[2], o[qt][1], 0, 0, 0);
            o[qt][1] = __builtin_amdgcn_mfma_f32_16x16x32_bf16(pf1, vf[3], o[qt][1], 0, 0, 0);
            lones[qt] = __builtin_amdgcn_mfma_f32_16x16x32_bf16(pf0, ones, lones[qt], 0, 0, 0);
            lones[qt] = __builtin_amdgcn_mfma_f32_16x16x32_bf16(pf1, ones, lones[qt], 0, 0, 0);
        }
    }

    // epilogue: bf16 partial O + fp32 partial l (lones rows align with o rows)
    const size_t obase = (size_t)(ks * BH + bh) * SEQ;
    #pragma unroll
    for (int qt = 0; qt < 4; qt++) {
        if (l16 == 0) {
            #pragma unroll
            for (int r = 0; r < 4; r++)
                pl[obase + q0 + qt * 16 + quad * 4 + r] = lones[qt][r];
        }
        #pragma unroll
        for (int r = 0; r < 4; r++) {
            int n = q0 + qt * 16 + quad * 4 + r;
            unsigned short* dst = po + (obase + n) * DH;
            dst[l16]      = f2bf(o[qt][0][r]);
            dst[16 + l16] = f2bf(o[qt][1][r]);
        }
    }
}

// ---------------- merge: sum bf16 split partials, divide, write out ---------
__global__ __launch_bounds__(256) void merge_kernel(
    const unsigned short* __restrict__ po, const float* __restrict__ pl,
    float* __restrict__ out)
{
    int t    = blockIdx.x * 256 + threadIdx.x;   // 0 .. 512K-1
    int d8   = t & 7;
    int pair = t >> 3;
    int bh   = pair >> 12;
    int n    = pair & 4095;
    float s0 = 0.f, s1 = 0.f, s2 = 0.f, s3 = 0.f, ls = 0.f;
    #pragma unroll
    for (int sp = 0; sp < NSPLIT; sp++) {
        size_t base = (size_t)(sp * BH + bh) * SEQ + n;
        uint2 v = ((const uint2*)(po + base * DH))[d8];
        s0 += __builtin_bit_cast(float, v.x << 16);
        s1 += __builtin_bit_cast(float, v.x & 0xFFFF0000u);
        s2 += __builtin_bit_cast(float, v.y << 16);
        s3 += __builtin_bit_cast(float, v.y & 0xFFFF0000u);
        ls += pl[base];
    }
    float inv = 1.f / ls;
    int b = bh >> 3, h = bh & 7;
    float4 o = {s0 * inv, s1 * inv, s2 * inv, s3 * inv};
    ((float4*)(out + ((size_t)b * SEQ + n) * (NH * DH) + h * DH))[d8] = o;
}

extern "C" void kernel_launch(void* const* d_in, const int* in_sizes, int n_in,
                              void* d_out, int out_size, void* d_ws, size_t ws_size,
                              hipStream_t stream)
{
    const float* x  = (const float*)d_in[0];
    const float* Wq = (const float*)d_in[1];
    const float* Wk = (const float*)d_in[2];
    const float* Wv = (const float*)d_in[3];
    float* out = (float*)d_out;

    // ws: qh|kh|vt (4 MiB each) | Wt (384 KiB) | po (32 MiB bf16) | pl (2 MiB f32)
    unsigned short* qh = (unsigned short*)d_ws;
    unsigned short* kh = qh + (size_t)BH * SEQ * DH;
    unsigned short* vt = kh + (size_t)BH * SEQ * DH;
    unsigned short* Wt = vt + (size_t)BH * SEQ * DH;
    unsigned short* po = Wt + 3 * DIN * DIN;
    float* pl = (float*)(po + (size_t)NSPLIT * BH * SEQ * DH);

    prep_kernel<<<dim3(48), 256, 0, stream>>>(Wq, Wk, Wv, Wt);
    proj_kernel<<<dim3(512, 3), 256, 0, stream>>>(x, Wt, qh, kh, vt);
    attn_kernel<<<dim3(BH * (SEQ / QTILE) * NSPLIT), 256, 0, stream>>>(qh, kh, vt, po, pl);
    merge_kernel<<<dim3(2048), 256, 0, stream>>>(po, pl, out);
}

// Round 14
// 170.897 us; speedup vs baseline: 2.2821x; 1.2047x over previous
//
#include <hip/hip_runtime.h>
#include <math.h>

#define BATCH 2
#define SEQ   4096
#define DIN   256
#define NH    8
#define DH    32            // head dim (dk = dv = 32)
#define BH    (BATCH*NH)    // 16
#define QTILE 64            // q rows per block (shared by all 4 waves)
#define KPW   (SEQ/4)       // 1024 keys per wave (in-block key split)
#define ITERS (KPW/32)      // 32 iters of 32 keys per wave

typedef short bf16x8 __attribute__((ext_vector_type(8)));
typedef float f32x4  __attribute__((ext_vector_type(4)));

// raw v_exp_f32 (base-2). Scores bounded -> no denorm fixup needed.
#if defined(__has_builtin)
#if __has_builtin(__builtin_amdgcn_exp2f)
#define EXP2(x) __builtin_amdgcn_exp2f(x)
#else
#define EXP2_ASM 1
#endif
#else
#define EXP2_ASM 1
#endif

// batch of 4 independent exp2: ONE trailing s_nop covers the trans-use hazard
__device__ __forceinline__ void exp4(float& a, float& b, float& c, float& d) {
#ifdef EXP2_ASM
    float r0, r1, r2, r3;
    asm("v_exp_f32 %0, %4\n\t"
        "v_exp_f32 %1, %5\n\t"
        "v_exp_f32 %2, %6\n\t"
        "v_exp_f32 %3, %7\n\t"
        "s_nop 1"
        : "=&v"(r0), "=&v"(r1), "=&v"(r2), "=&v"(r3)
        : "v"(a), "v"(b), "v"(c), "v"(d));
    a = r0; b = r1; c = r2; d = r3;
#else
    a = EXP2(a); b = EXP2(b); c = EXP2(c); d = EXP2(d);
#endif
}

#define SC2 0.25508218f     // log2(e)/sqrt(32) — folded into Q at projection

__device__ __forceinline__ unsigned short f2bf(float f) {
    unsigned int u = __builtin_bit_cast(unsigned int, f);
    u += 0x7fffu + ((u >> 16) & 1u);
    return (unsigned short)(u >> 16);
}

// pack 2 rounded bf16 (round-half-up), one v_perm + 2 adds
__device__ __forceinline__ unsigned int pack_bf2(float f0, float f1) {
    unsigned int u0 = __builtin_bit_cast(unsigned int, f0) + 0x8000u;
    unsigned int u1 = __builtin_bit_cast(unsigned int, f1) + 0x8000u;
    return __builtin_amdgcn_perm(u1, u0, 0x07060302u);
}

// pack 2 TRUNCATED bf16, single v_perm (hot attn loop). Truncation bias
// cancels exactly in softmax: l is computed from the same truncated P.
__device__ __forceinline__ unsigned int pack_bf2_t(float f0, float f1) {
    return __builtin_amdgcn_perm(__builtin_bit_cast(unsigned int, f1),
                                 __builtin_bit_cast(unsigned int, f0),
                                 0x07060302u);
}

#if defined(__has_builtin)
#if __has_builtin(__builtin_amdgcn_global_load_lds)
#define HAS_ASYNC_LDS 1
#endif
#endif

// async global->LDS, 16B/lane: wave-uniform LDS base, HW scatters lane i to
// base + i*16 (verified R5-R13).
__device__ __forceinline__ void stage16(const unsigned short* g,
                                        unsigned short* lds_base, int lane) {
#ifdef HAS_ASYNC_LDS
    __builtin_amdgcn_global_load_lds(
        (const __attribute__((address_space(1))) unsigned int*)g,
        (__attribute__((address_space(3))) unsigned int*)lds_base, 16, 0, 0);
#else
    *(bf16x8*)(lds_base + (size_t)lane * 8) = *(const bf16x8*)g;
#endif
}

// ---------------- prep: W -> Wt[t][k] bf16 (48 blocks) ----------------
__global__ __launch_bounds__(256) void prep_kernel(
    const float* __restrict__ Wq, const float* __restrict__ Wk, const float* __restrict__ Wv,
    unsigned short* __restrict__ Wt)
{
    __shared__ float ws[64][65];
    const int t = threadIdx.x;
    int wsel = blockIdx.x >> 4;
    int tile = blockIdx.x & 15;
    int tr = (tile >> 2) * 64;
    int tc = (tile & 3) * 64;
    const float* __restrict__ W = (wsel == 0) ? Wq : (wsel == 1) ? Wk : Wv;
    #pragma unroll
    for (int i = 0; i < 16; i++) {
        int row = i * 4 + (t >> 6), col = t & 63;
        ws[row][col] = W[(size_t)(tr + row) * DIN + tc + col];
    }
    __syncthreads();
    unsigned short* dst = Wt + (size_t)wsel * DIN * DIN;
    #pragma unroll
    for (int i = 0; i < 16; i++) {
        int orow = i * 4 + (t >> 6), ocol = t & 63;
        dst[(size_t)(tc + orow) * DIN + tr + ocol] = f2bf(ws[ocol][orow]);
    }
}

// ---------------- proj (R8-proven): x staged fp32->bf16 in-kernel ----------
__global__ __launch_bounds__(256) void proj_kernel(
    const float* __restrict__ x, const unsigned short* __restrict__ Wt,
    unsigned short* __restrict__ qh, unsigned short* __restrict__ kh,
    unsigned short* __restrict__ vt)
{
    __shared__ __align__(16) unsigned short abuf[8][4][64][8];  // 32 KiB
    __shared__ __align__(16) unsigned short bbuf[8][4][64][8];  // 32 KiB

    const int wsel = blockIdx.y;
    const int w    = threadIdx.x >> 6;
    const int lane = threadIdx.x & 63;
    const int quad = lane >> 4;
    const int l16  = lane & 15;

    const int sl   = lane ^ (lane >> 3);      // producer: lane -> slot
    const int sl16 = sl >> 2, squad = sl & 3;
    const int s_ = (l16 << 2) | quad;         // consumer slot for (l16, quad)
    const int jj = (s_ & 56) | ((s_ ^ (s_ >> 3)) & 7);

    int arow0, brow0;
    const unsigned short* Wbase;
    const float* Xbase;
    unsigned short (*wdst)[4][64][8];
    unsigned short (*xdst)[4][64][8];
    if (wsel < 2) {
        int tt = blockIdx.x >> 7, nt = blockIdx.x & 127;
        arow0 = tt * 64; brow0 = nt * 64;
        Wbase = Wt + (size_t)wsel * DIN * DIN + (size_t)arow0 * DIN;
        Xbase = x + (size_t)brow0 * DIN;
        wdst = abuf; xdst = bbuf;
    } else {
        int nt = blockIdx.x >> 2, tt = blockIdx.x & 3;
        arow0 = nt * 64; brow0 = tt * 64;
        Xbase = x + (size_t)arow0 * DIN;
        Wbase = Wt + (size_t)2 * DIN * DIN + (size_t)brow0 * DIN;
        wdst = bbuf; xdst = abuf;
    }

    #pragma unroll
    for (int i = 0; i < 8; i++) {
        int id = w * 8 + i;
        int kb = id >> 2, rt = id & 3;
        stage16(Wbase + (size_t)(rt * 16 + sl16) * DIN + kb * 32 + squad * 8,
                &wdst[kb][rt][0][0], lane);
    }
    #pragma unroll
    for (int i = 0; i < 8; i++) {
        int id = w * 8 + i;
        int kb = id >> 2, rt = id & 3;
        const float4* src = (const float4*)(Xbase + (size_t)(rt * 16 + sl16) * DIN
                                            + kb * 32 + squad * 8);
        float4 a = src[0], b = src[1];
        uint4 p = { pack_bf2(a.x, a.y), pack_bf2(a.z, a.w),
                    pack_bf2(b.x, b.y), pack_bf2(b.z, b.w) };
        *(uint4*)(&xdst[kb][rt][0][0] + (size_t)lane * 8) = p;
    }
    __syncthreads();

    f32x4 acc[4];
    #pragma unroll
    for (int c = 0; c < 4; c++) acc[c] = (f32x4){0.f, 0.f, 0.f, 0.f};
    #pragma unroll
    for (int kb = 0; kb < 8; kb++) {
        bf16x8 af = *(const bf16x8*)&abuf[kb][w][jj][0];
        #pragma unroll
        for (int c = 0; c < 4; c++) {
            bf16x8 bfr = *(const bf16x8*)&bbuf[kb][c][jj][0];
            acc[c] = __builtin_amdgcn_mfma_f32_16x16x32_bf16(af, bfr, acc[c], 0, 0, 0);
        }
    }

    if (wsel < 2) {
        const float scl = (wsel == 0) ? SC2 : 1.0f;
        unsigned short* __restrict__ dst0 = (wsel == 0) ? qh : kh;
        const int t0 = arow0 + w * 16;
        const int h = t0 >> 5, d0 = (t0 & 31) + quad * 4;
        #pragma unroll
        for (int c = 0; c < 4; c++) {
            int n = brow0 + c * 16 + l16;
            int b = n >> 12, n12 = n & 4095;
            unsigned int u01 = pack_bf2(acc[c][0] * scl, acc[c][1] * scl);
            unsigned int u23 = pack_bf2(acc[c][2] * scl, acc[c][3] * scl);
            *(uint2*)&dst0[((size_t)(b * NH + h) * SEQ + n12) * DH + d0] = make_uint2(u01, u23);
        }
    } else {
        const int n0w = arow0 + w * 16;
        const int b = n0w >> 12, nbase = (n0w & 4095) + quad * 4;
        #pragma unroll
        for (int c = 0; c < 4; c++) {
            int t = brow0 + c * 16;
            int h = t >> 5, d = (t & 31) + l16;
            unsigned int u01 = pack_bf2(acc[c][0], acc[c][1]);
            unsigned int u23 = pack_bf2(acc[c][2], acc[c][3]);
            *(uint2*)&vt[((size_t)(b * NH + h) * DH + d) * SEQ + nbase] = make_uint2(u01, u23);
        }
    }
}

// ---------------- Flash attention v14: wave-private staging + vmcnt(4) ------
// R10 structure (block = 64 q x 4096 keys; wave w owns keys [w*1024,(w+1)*1024),
// NO barrier in the K-loop) + the AITER-style fix: never wait vmcnt(0) in the
// steady state. 2-buffer ring: at top of iter t wait vmcnt(4) (tile t landed,
// tile t+1 still in flight); read fragments; compute; at bottom issue tile t+2
// into buf[t&1] (its ds_reads drained long before). Final iter waits vmcnt(0).
// LDS = 16K kbuf + 16K vbuf + 8K pbuf = 40960 B -> exactly 4 blocks/CU.
__global__ __launch_bounds__(256) void attn_kernel(
    const unsigned short* __restrict__ qh,
    const unsigned short* __restrict__ kh,
    const unsigned short* __restrict__ vt,
    float* __restrict__ out)
{
    __shared__ __align__(16) unsigned char smem[40960];
    unsigned short (*kbuf)[2][2][64][8] = (unsigned short (*)[2][2][64][8])smem;            // [wave][buf][frag]
    unsigned short (*vbuf)[2][2][64][8] = (unsigned short (*)[2][2][64][8])(smem + 16384);  // [wave][buf][dh]
    unsigned short (*pbuf)[2][16][32]   = (unsigned short (*)[2][16][32])(smem + 32768);    // [wave][parity][q16][32k]

    const int tid  = threadIdx.x;
    const int wave = tid >> 6;
    const int lane = tid & 63;
    const int quad = lane >> 4;
    const int l16  = lane & 15;

    const int sl   = lane ^ (lane >> 3);      // producer: lane -> fragment slot
    const int sl16 = sl >> 2, squad = sl & 3;
    const int s_   = (l16 << 2) | quad;       // consumer slot
    const int jj   = (s_ & 56) | ((s_ ^ (s_ >> 3)) & 7);

    const int bh = blockIdx.x & 15;           // head -> XCD pinning
    const int qb = blockIdx.x >> 4;           // 0..63
    const int q0 = qb * QTILE;
    const int kstart = wave * KPW;

    const unsigned short* __restrict__ Qp = qh + (size_t)bh * SEQ * DH;
    const unsigned short* __restrict__ Kp = kh + (size_t)bh * SEQ * DH;
    const unsigned short* __restrict__ Vp = vt + (size_t)bh * DH * SEQ;

    // Q fragments (B-operand), 4 q-subtiles of 16, pre-scaled by SC2
    bf16x8 qf[4];
    #pragma unroll
    for (int i = 0; i < 4; i++)
        qf[i] = *(const bf16x8*)(Qp + (size_t)(q0 + i * 16 + l16) * DH + quad * 8);

    const bf16x8 ones = {0x3F80, 0x3F80, 0x3F80, 0x3F80,
                         0x3F80, 0x3F80, 0x3F80, 0x3F80};

    f32x4 o[4][2];
    f32x4 lones[4];
    #pragma unroll
    for (int i = 0; i < 4; i++) {
        o[i][0] = (f32x4){0.f, 0.f, 0.f, 0.f};
        o[i][1] = (f32x4){0.f, 0.f, 0.f, 0.f};
        lones[i] = (f32x4){0.f, 0.f, 0.f, 0.f};
    }
    const f32x4 z = {0.f, 0.f, 0.f, 0.f};

    // staging sources (advance per tile): K tile = 32 keys x 32 dh (2 dmas),
    // V tile = 32 d x 32 keys (2 dmas). Mapping verified in R10.
    const unsigned short* ksrc0 = Kp + (size_t)(kstart +      sl16) * DH + squad * 8;
    const unsigned short* ksrc1 = Kp + (size_t)(kstart + 16 + sl16) * DH + squad * 8;
    const unsigned short* vsrc0 = Vp + (size_t)(     sl16) * SEQ + kstart + squad * 8;
    const unsigned short* vsrc1 = Vp + (size_t)(16 + sl16) * SEQ + kstart + squad * 8;

    #define ISSUE_TILE(B_)                                        \
        do {                                                      \
            stage16(ksrc0, &kbuf[wave][B_][0][0][0], lane);       \
            stage16(ksrc1, &kbuf[wave][B_][1][0][0], lane);       \
            stage16(vsrc0, &vbuf[wave][B_][0][0][0], lane);       \
            stage16(vsrc1, &vbuf[wave][B_][1][0][0], lane);       \
            ksrc0 += 32 * DH; ksrc1 += 32 * DH;                   \
            vsrc0 += 32;      vsrc1 += 32;                        \
        } while (0)

    // prologue: tiles 0 and 1 in flight
    ISSUE_TILE(0);
    ISSUE_TILE(1);

    for (int t = 0; t < ITERS; t++) {
        const int buf = t & 1;

        if (t + 1 < ITERS)
            __builtin_amdgcn_s_waitcnt(0x3F74);   // vmcnt(4): tile t landed, t+1 in flight
        else
            __builtin_amdgcn_s_waitcnt(0x3F70);   // vmcnt(0): final tile

        bf16x8 kf0 = *(const bf16x8*)&kbuf[wave][buf][0][jj][0];
        bf16x8 kf1 = *(const bf16x8*)&kbuf[wave][buf][1][jj][0];
        bf16x8 vf0 = *(const bf16x8*)&vbuf[wave][buf][0][jj][0];
        bf16x8 vf1 = *(const bf16x8*)&vbuf[wave][buf][1][jj][0];

        #pragma unroll
        for (int qt = 0; qt < 4; qt++) {
            const int pr = qt & 1;    // parity region: adjacent qt chains overlap
            // S^T = K(32k) x Q^T(16q): rows = keys, cols = q
            f32x4 s0 = __builtin_amdgcn_mfma_f32_16x16x32_bf16(kf0, qf[qt], z, 0, 0, 0);
            f32x4 s1 = __builtin_amdgcn_mfma_f32_16x16x32_bf16(kf1, qf[qt], z, 0, 0, 0);
            float e0 = s0[0], e1 = s0[1], e2 = s0[2], e3 = s0[3];
            float e4 = s1[0], e5 = s1[1], e6 = s1[2], e7 = s1[3];
            exp4(e0, e1, e2, e3);
            exp4(e4, e5, e6, e7);
            *(uint2*)&pbuf[wave][pr][l16][quad * 4] =
                make_uint2(pack_bf2_t(e0, e1), pack_bf2_t(e2, e3));
            *(uint2*)&pbuf[wave][pr][l16][16 + quad * 4] =
                make_uint2(pack_bf2_t(e4, e5), pack_bf2_t(e6, e7));
            // P A-fragment: full 32-key contraction in one b128 read
            bf16x8 pf = *(const bf16x8*)&pbuf[wave][pr][l16][quad * 8];
            o[qt][0] = __builtin_amdgcn_mfma_f32_16x16x32_bf16(pf, vf0, o[qt][0], 0, 0, 0);
            o[qt][1] = __builtin_amdgcn_mfma_f32_16x16x32_bf16(pf, vf1, o[qt][1], 0, 0, 0);
            lones[qt] = __builtin_amdgcn_mfma_f32_16x16x32_bf16(pf, ones, lones[qt], 0, 0, 0);
        }

        // issue tile t+2 into the buffer just consumed (reads drained above)
        if (t + 2 < ITERS)
            ISSUE_TILE(buf);
    }
    #undef ISSUE_TILE

    // ---------------- epilogue: cross-wave reduction, direct out ----------------
    __syncthreads();   // all waves done with kbuf/vbuf -> reuse as ored
    unsigned short (*ored)[QTILE][40] = (unsigned short (*)[QTILE][40])smem;     // 20.5 KiB
    float (*lred)[QTILE] = (float (*)[QTILE])(smem + 32768);                     // 1 KiB

    #pragma unroll
    for (int qt = 0; qt < 4; qt++) {
        #pragma unroll
        for (int r = 0; r < 4; r++) {
            int q = qt * 16 + quad * 4 + r;
            ored[wave][q][l16]      = f2bf(o[qt][0][r]);
            ored[wave][q][16 + l16] = f2bf(o[qt][1][r]);
            if (l16 == 0) lred[wave][q] = lones[qt][r];
        }
    }
    __syncthreads();

    const int b = bh >> 3, h = bh & 7;
    const int q  = tid >> 2;            // 0..63
    const int d0 = (tid & 3) * 8;       // 0,8,16,24
    float acc[8];
    #pragma unroll
    for (int j = 0; j < 8; j++) acc[j] = 0.f;
    #pragma unroll
    for (int w = 0; w < 4; w++) {
        uint4 v = *(const uint4*)&ored[w][q][d0];
        acc[0] += __builtin_bit_cast(float, v.x << 16);
        acc[1] += __builtin_bit_cast(float, v.x & 0xFFFF0000u);
        acc[2] += __builtin_bit_cast(float, v.y << 16);
        acc[3] += __builtin_bit_cast(float, v.y & 0xFFFF0000u);
        acc[4] += __builtin_bit_cast(float, v.z << 16);
        acc[5] += __builtin_bit_cast(float, v.z & 0xFFFF0000u);
        acc[6] += __builtin_bit_cast(float, v.w << 16);
        acc[7] += __builtin_bit_cast(float, v.w & 0xFFFF0000u);
    }
    float ls = (lred[0][q] + lred[1][q]) + (lred[2][q] + lred[3][q]);
    float inv = 1.f / ls;
    float* dst = out + ((size_t)b * SEQ + q0 + q) * (NH * DH) + h * DH + d0;
    float4 o0 = {acc[0] * inv, acc[1] * inv, acc[2] * inv, acc[3] * inv};
    float4 o1 = {acc[4] * inv, acc[5] * inv, acc[6] * inv, acc[7] * inv};
    ((float4*)dst)[0] = o0;
    ((float4*)dst)[1] = o1;
}

extern "C" void kernel_launch(void* const* d_in, const int* in_sizes, int n_in,
                              void* d_out, int out_size, void* d_ws, size_t ws_size,
                              hipStream_t stream)
{
    const float* x  = (const float*)d_in[0];
    const float* Wq = (const float*)d_in[1];
    const float* Wk = (const float*)d_in[2];
    const float* Wv = (const float*)d_in[3];
    float* out = (float*)d_out;

    // ws: qh | kh | vt (4 MiB each) | Wt (384 KiB)
    unsigned short* qh = (unsigned short*)d_ws;
    unsigned short* kh = qh + (size_t)BH * SEQ * DH;
    unsigned short* vt = kh + (size_t)BH * SEQ * DH;
    unsigned short* Wt = vt + (size_t)BH * SEQ * DH;

    prep_kernel<<<dim3(48), 256, 0, stream>>>(Wq, Wk, Wv, Wt);
    proj_kernel<<<dim3(512, 3), 256, 0, stream>>>(x, Wt, qh, kh, vt);
    attn_kernel<<<dim3(BH * (SEQ / QTILE)), 256, 0, stream>>>(qh, kh, vt, out);
}

// Round 15
// 146.275 us; speedup vs baseline: 2.6663x; 1.1683x over previous
//
#include <hip/hip_runtime.h>
#include <math.h>

#define BATCH 2
#define SEQ   4096
#define DIN   256
#define NH    8
#define DH    32            // head dim (dk = dv = 32)
#define BH    (BATCH*NH)    // 16
#define QTILE 64            // q rows per block (shared by all 4 waves)
#define KPW   (SEQ/4)       // 1024 keys per wave (in-block key split)
#define ITERS (KPW/32)      // 32 iters of 32 keys per wave

typedef short bf16x8 __attribute__((ext_vector_type(8)));
typedef float f32x4  __attribute__((ext_vector_type(4)));

// raw v_exp_f32 (base-2). Scores bounded -> no denorm fixup needed.
#if defined(__has_builtin)
#if __has_builtin(__builtin_amdgcn_exp2f)
#define EXP2(x) __builtin_amdgcn_exp2f(x)
#else
#define EXP2_ASM 1
#endif
#else
#define EXP2_ASM 1
#endif

// batch of 4 independent exp2: ONE trailing s_nop covers the trans-use hazard
__device__ __forceinline__ void exp4(float& a, float& b, float& c, float& d) {
#ifdef EXP2_ASM
    float r0, r1, r2, r3;
    asm("v_exp_f32 %0, %4\n\t"
        "v_exp_f32 %1, %5\n\t"
        "v_exp_f32 %2, %6\n\t"
        "v_exp_f32 %3, %7\n\t"
        "s_nop 1"
        : "=&v"(r0), "=&v"(r1), "=&v"(r2), "=&v"(r3)
        : "v"(a), "v"(b), "v"(c), "v"(d));
    a = r0; b = r1; c = r2; d = r3;
#else
    a = EXP2(a); b = EXP2(b); c = EXP2(c); d = EXP2(d);
#endif
}

#define SC2 0.25508218f     // log2(e)/sqrt(32) — folded into Q at projection

__device__ __forceinline__ unsigned short f2bf(float f) {
    unsigned int u = __builtin_bit_cast(unsigned int, f);
    u += 0x7fffu + ((u >> 16) & 1u);
    return (unsigned short)(u >> 16);
}

// pack 2 rounded bf16 (round-half-up), one v_perm + 2 adds
__device__ __forceinline__ unsigned int pack_bf2(float f0, float f1) {
    unsigned int u0 = __builtin_bit_cast(unsigned int, f0) + 0x8000u;
    unsigned int u1 = __builtin_bit_cast(unsigned int, f1) + 0x8000u;
    return __builtin_amdgcn_perm(u1, u0, 0x07060302u);
}

// pack 2 TRUNCATED bf16, single v_perm (hot attn loop). Truncation bias
// cancels exactly in softmax: l is computed from the same truncated P.
__device__ __forceinline__ unsigned int pack_bf2_t(float f0, float f1) {
    return __builtin_amdgcn_perm(__builtin_bit_cast(unsigned int, f1),
                                 __builtin_bit_cast(unsigned int, f0),
                                 0x07060302u);
}

#if defined(__has_builtin)
#if __has_builtin(__builtin_amdgcn_global_load_lds)
#define HAS_ASYNC_LDS 1
#endif
#endif

// async global->LDS, 16B/lane: wave-uniform LDS base, HW scatters lane i to
// base + i*16 (verified R5-R14).
__device__ __forceinline__ void stage16(const unsigned short* g,
                                        unsigned short* lds_base, int lane) {
#ifdef HAS_ASYNC_LDS
    __builtin_amdgcn_global_load_lds(
        (const __attribute__((address_space(1))) unsigned int*)g,
        (__attribute__((address_space(3))) unsigned int*)lds_base, 16, 0, 0);
#else
    *(bf16x8*)(lds_base + (size_t)lane * 8) = *(const bf16x8*)g;
#endif
}

// ---------------- prep: W -> Wt[t][k] bf16 (48 blocks) ----------------
__global__ __launch_bounds__(256) void prep_kernel(
    const float* __restrict__ Wq, const float* __restrict__ Wk, const float* __restrict__ Wv,
    unsigned short* __restrict__ Wt)
{
    __shared__ float ws[64][65];
    const int t = threadIdx.x;
    int wsel = blockIdx.x >> 4;
    int tile = blockIdx.x & 15;
    int tr = (tile >> 2) * 64;
    int tc = (tile & 3) * 64;
    const float* __restrict__ W = (wsel == 0) ? Wq : (wsel == 1) ? Wk : Wv;
    #pragma unroll
    for (int i = 0; i < 16; i++) {
        int row = i * 4 + (t >> 6), col = t & 63;
        ws[row][col] = W[(size_t)(tr + row) * DIN + tc + col];
    }
    __syncthreads();
    unsigned short* dst = Wt + (size_t)wsel * DIN * DIN;
    #pragma unroll
    for (int i = 0; i < 16; i++) {
        int orow = i * 4 + (t >> 6), ocol = t & 63;
        dst[(size_t)(tc + orow) * DIN + tr + ocol] = f2bf(ws[ocol][orow]);
    }
}

// ---------------- proj (R8-proven): x staged fp32->bf16 in-kernel ----------
__global__ __launch_bounds__(256) void proj_kernel(
    const float* __restrict__ x, const unsigned short* __restrict__ Wt,
    unsigned short* __restrict__ qh, unsigned short* __restrict__ kh,
    unsigned short* __restrict__ vt)
{
    __shared__ __align__(16) unsigned short abuf[8][4][64][8];  // 32 KiB
    __shared__ __align__(16) unsigned short bbuf[8][4][64][8];  // 32 KiB

    const int wsel = blockIdx.y;
    const int w    = threadIdx.x >> 6;
    const int lane = threadIdx.x & 63;
    const int quad = lane >> 4;
    const int l16  = lane & 15;

    const int sl   = lane ^ (lane >> 3);      // producer: lane -> slot
    const int sl16 = sl >> 2, squad = sl & 3;
    const int s_ = (l16 << 2) | quad;         // consumer slot for (l16, quad)
    const int jj = (s_ & 56) | ((s_ ^ (s_ >> 3)) & 7);

    int arow0, brow0;
    const unsigned short* Wbase;
    const float* Xbase;
    unsigned short (*wdst)[4][64][8];
    unsigned short (*xdst)[4][64][8];
    if (wsel < 2) {
        int tt = blockIdx.x >> 7, nt = blockIdx.x & 127;
        arow0 = tt * 64; brow0 = nt * 64;
        Wbase = Wt + (size_t)wsel * DIN * DIN + (size_t)arow0 * DIN;
        Xbase = x + (size_t)brow0 * DIN;
        wdst = abuf; xdst = bbuf;
    } else {
        int nt = blockIdx.x >> 2, tt = blockIdx.x & 3;
        arow0 = nt * 64; brow0 = tt * 64;
        Xbase = x + (size_t)arow0 * DIN;
        Wbase = Wt + (size_t)2 * DIN * DIN + (size_t)brow0 * DIN;
        wdst = bbuf; xdst = abuf;
    }

    #pragma unroll
    for (int i = 0; i < 8; i++) {
        int id = w * 8 + i;
        int kb = id >> 2, rt = id & 3;
        stage16(Wbase + (size_t)(rt * 16 + sl16) * DIN + kb * 32 + squad * 8,
                &wdst[kb][rt][0][0], lane);
    }
    #pragma unroll
    for (int i = 0; i < 8; i++) {
        int id = w * 8 + i;
        int kb = id >> 2, rt = id & 3;
        const float4* src = (const float4*)(Xbase + (size_t)(rt * 16 + sl16) * DIN
                                            + kb * 32 + squad * 8);
        float4 a = src[0], b = src[1];
        uint4 p = { pack_bf2(a.x, a.y), pack_bf2(a.z, a.w),
                    pack_bf2(b.x, b.y), pack_bf2(b.z, b.w) };
        *(uint4*)(&xdst[kb][rt][0][0] + (size_t)lane * 8) = p;
    }
    __syncthreads();

    f32x4 acc[4];
    #pragma unroll
    for (int c = 0; c < 4; c++) acc[c] = (f32x4){0.f, 0.f, 0.f, 0.f};
    #pragma unroll
    for (int kb = 0; kb < 8; kb++) {
        bf16x8 af = *(const bf16x8*)&abuf[kb][w][jj][0];
        #pragma unroll
        for (int c = 0; c < 4; c++) {
            bf16x8 bfr = *(const bf16x8*)&bbuf[kb][c][jj][0];
            acc[c] = __builtin_amdgcn_mfma_f32_16x16x32_bf16(af, bfr, acc[c], 0, 0, 0);
        }
    }

    if (wsel < 2) {
        const float scl = (wsel == 0) ? SC2 : 1.0f;
        unsigned short* __restrict__ dst0 = (wsel == 0) ? qh : kh;
        const int t0 = arow0 + w * 16;
        const int h = t0 >> 5, d0 = (t0 & 31) + quad * 4;
        #pragma unroll
        for (int c = 0; c < 4; c++) {
            int n = brow0 + c * 16 + l16;
            int b = n >> 12, n12 = n & 4095;
            unsigned int u01 = pack_bf2(acc[c][0] * scl, acc[c][1] * scl);
            unsigned int u23 = pack_bf2(acc[c][2] * scl, acc[c][3] * scl);
            *(uint2*)&dst0[((size_t)(b * NH + h) * SEQ + n12) * DH + d0] = make_uint2(u01, u23);
        }
    } else {
        const int n0w = arow0 + w * 16;
        const int b = n0w >> 12, nbase = (n0w & 4095) + quad * 4;
        #pragma unroll
        for (int c = 0; c < 4; c++) {
            int t = brow0 + c * 16;
            int h = t >> 5, d = (t & 31) + l16;
            unsigned int u01 = pack_bf2(acc[c][0], acc[c][1]);
            unsigned int u23 = pack_bf2(acc[c][2], acc[c][3]);
            *(uint2*)&vt[((size_t)(b * NH + h) * DH + d) * SEQ + nbase] = make_uint2(u01, u23);
        }
    }
}

// ---------------- Flash attention v15: R14 pipeline + conflict-free pbuf ----
// R14's no-barrier wave-private staging with vmcnt(4) 2-buffer ring, but pbuf
// back to R10's proven stride-40 layout (80 B rows: b64 writes at the balanced
// 4-access/bank floor, b128 reads 2-way = free). Parity dim dropped (R8: neutral;
// DS ops are in-order per wave so WAR is free). LDS 37888 B -> 4 blocks/CU.
__global__ __launch_bounds__(256) void attn_kernel(
    const unsigned short* __restrict__ qh,
    const unsigned short* __restrict__ kh,
    const unsigned short* __restrict__ vt,
    float* __restrict__ out)
{
    __shared__ __align__(16) unsigned char smem[37888];
    unsigned short (*kbuf)[2][2][64][8] = (unsigned short (*)[2][2][64][8])smem;            // [wave][buf][frag]
    unsigned short (*vbuf)[2][2][64][8] = (unsigned short (*)[2][2][64][8])(smem + 16384);  // [wave][buf][dh]
    unsigned short (*pbuf)[16][40]      = (unsigned short (*)[16][40])(smem + 32768);       // [wave][q16][40]

    const int tid  = threadIdx.x;
    const int wave = tid >> 6;
    const int lane = tid & 63;
    const int quad = lane >> 4;
    const int l16  = lane & 15;

    const int sl   = lane ^ (lane >> 3);      // producer: lane -> fragment slot
    const int sl16 = sl >> 2, squad = sl & 3;
    const int s_   = (l16 << 2) | quad;       // consumer slot
    const int jj   = (s_ & 56) | ((s_ ^ (s_ >> 3)) & 7);

    const int bh = blockIdx.x & 15;           // head -> XCD pinning
    const int qb = blockIdx.x >> 4;           // 0..63
    const int q0 = qb * QTILE;
    const int kstart = wave * KPW;

    const unsigned short* __restrict__ Qp = qh + (size_t)bh * SEQ * DH;
    const unsigned short* __restrict__ Kp = kh + (size_t)bh * SEQ * DH;
    const unsigned short* __restrict__ Vp = vt + (size_t)bh * DH * SEQ;

    // Q fragments (B-operand), 4 q-subtiles of 16, pre-scaled by SC2
    bf16x8 qf[4];
    #pragma unroll
    for (int i = 0; i < 4; i++)
        qf[i] = *(const bf16x8*)(Qp + (size_t)(q0 + i * 16 + l16) * DH + quad * 8);

    const bf16x8 ones = {0x3F80, 0x3F80, 0x3F80, 0x3F80,
                         0x3F80, 0x3F80, 0x3F80, 0x3F80};

    f32x4 o[4][2];
    f32x4 lones[4];
    #pragma unroll
    for (int i = 0; i < 4; i++) {
        o[i][0] = (f32x4){0.f, 0.f, 0.f, 0.f};
        o[i][1] = (f32x4){0.f, 0.f, 0.f, 0.f};
        lones[i] = (f32x4){0.f, 0.f, 0.f, 0.f};
    }
    const f32x4 z = {0.f, 0.f, 0.f, 0.f};

    // staging sources (advance per tile): K tile = 32 keys x 32 dh (2 dmas),
    // V tile = 32 d x 32 keys (2 dmas). Mapping verified R10/R14.
    const unsigned short* ksrc0 = Kp + (size_t)(kstart +      sl16) * DH + squad * 8;
    const unsigned short* ksrc1 = Kp + (size_t)(kstart + 16 + sl16) * DH + squad * 8;
    const unsigned short* vsrc0 = Vp + (size_t)(     sl16) * SEQ + kstart + squad * 8;
    const unsigned short* vsrc1 = Vp + (size_t)(16 + sl16) * SEQ + kstart + squad * 8;

    #define ISSUE_TILE(B_)                                        \
        do {                                                      \
            stage16(ksrc0, &kbuf[wave][B_][0][0][0], lane);       \
            stage16(ksrc1, &kbuf[wave][B_][1][0][0], lane);       \
            stage16(vsrc0, &vbuf[wave][B_][0][0][0], lane);       \
            stage16(vsrc1, &vbuf[wave][B_][1][0][0], lane);       \
            ksrc0 += 32 * DH; ksrc1 += 32 * DH;                   \
            vsrc0 += 32;      vsrc1 += 32;                        \
        } while (0)

    // prologue: tiles 0 and 1 in flight
    ISSUE_TILE(0);
    ISSUE_TILE(1);

    for (int t = 0; t < ITERS; t++) {
        const int buf = t & 1;

        if (t + 1 < ITERS)
            __builtin_amdgcn_s_waitcnt(0x3F74);   // vmcnt(4): tile t landed, t+1 in flight
        else
            __builtin_amdgcn_s_waitcnt(0x3F70);   // vmcnt(0): final tile

        bf16x8 kf0 = *(const bf16x8*)&kbuf[wave][buf][0][jj][0];
        bf16x8 kf1 = *(const bf16x8*)&kbuf[wave][buf][1][jj][0];
        bf16x8 vf0 = *(const bf16x8*)&vbuf[wave][buf][0][jj][0];
        bf16x8 vf1 = *(const bf16x8*)&vbuf[wave][buf][1][jj][0];

        #pragma unroll
        for (int qt = 0; qt < 4; qt++) {
            // S^T = K(32k) x Q^T(16q): rows = keys, cols = q
            f32x4 s0 = __builtin_amdgcn_mfma_f32_16x16x32_bf16(kf0, qf[qt], z, 0, 0, 0);
            f32x4 s1 = __builtin_amdgcn_mfma_f32_16x16x32_bf16(kf1, qf[qt], z, 0, 0, 0);
            float e0 = s0[0], e1 = s0[1], e2 = s0[2], e3 = s0[3];
            float e4 = s1[0], e5 = s1[1], e6 = s1[2], e7 = s1[3];
            exp4(e0, e1, e2, e3);
            exp4(e4, e5, e6, e7);
            // P[q=l16][keys quad*4.. / 16+quad*4..]: b64 writes, stride-40 rows
            *(uint2*)&pbuf[wave][l16][quad * 4] =
                make_uint2(pack_bf2_t(e0, e1), pack_bf2_t(e2, e3));
            *(uint2*)&pbuf[wave][l16][16 + quad * 4] =
                make_uint2(pack_bf2_t(e4, e5), pack_bf2_t(e6, e7));
            // P A-fragment: full 32-key contraction in one b128 read (2-way banks)
            bf16x8 pf = *(const bf16x8*)&pbuf[wave][l16][quad * 8];
            o[qt][0] = __builtin_amdgcn_mfma_f32_16x16x32_bf16(pf, vf0, o[qt][0], 0, 0, 0);
            o[qt][1] = __builtin_amdgcn_mfma_f32_16x16x32_bf16(pf, vf1, o[qt][1], 0, 0, 0);
            lones[qt] = __builtin_amdgcn_mfma_f32_16x16x32_bf16(pf, ones, lones[qt], 0, 0, 0);
        }

        // issue tile t+2 into the buffer just consumed (reads drained above)
        if (t + 2 < ITERS)
            ISSUE_TILE(buf);
    }
    #undef ISSUE_TILE

    // ---------------- epilogue: cross-wave reduction, direct out ----------------
    __syncthreads();   // all waves done with kbuf/vbuf -> reuse as ored
    unsigned short (*ored)[QTILE][40] = (unsigned short (*)[QTILE][40])smem;     // 20.5 KiB
    float (*lred)[QTILE] = (float (*)[QTILE])(smem + 32768);                     // 1 KiB

    #pragma unroll
    for (int qt = 0; qt < 4; qt++) {
        #pragma unroll
        for (int r = 0; r < 4; r++) {
            int q = qt * 16 + quad * 4 + r;
            ored[wave][q][l16]      = f2bf(o[qt][0][r]);
            ored[wave][q][16 + l16] = f2bf(o[qt][1][r]);
            if (l16 == 0) lred[wave][q] = lones[qt][r];
        }
    }
    __syncthreads();

    const int b = bh >> 3, h = bh & 7;
    const int q  = tid >> 2;            // 0..63
    const int d0 = (tid & 3) * 8;       // 0,8,16,24
    float acc[8];
    #pragma unroll
    for (int j = 0; j < 8; j++) acc[j] = 0.f;
    #pragma unroll
    for (int w = 0; w < 4; w++) {
        uint4 v = *(const uint4*)&ored[w][q][d0];
        acc[0] += __builtin_bit_cast(float, v.x << 16);
        acc[1] += __builtin_bit_cast(float, v.x & 0xFFFF0000u);
        acc[2] += __builtin_bit_cast(float, v.y << 16);
        acc[3] += __builtin_bit_cast(float, v.y & 0xFFFF0000u);
        acc[4] += __builtin_bit_cast(float, v.z << 16);
        acc[5] += __builtin_bit_cast(float, v.z & 0xFFFF0000u);
        acc[6] += __builtin_bit_cast(float, v.w << 16);
        acc[7] += __builtin_bit_cast(float, v.w & 0xFFFF0000u);
    }
    float ls = (lred[0][q] + lred[1][q]) + (lred[2][q] + lred[3][q]);
    float inv = 1.f / ls;
    float* dst = out + ((size_t)b * SEQ + q0 + q) * (NH * DH) + h * DH + d0;
    float4 o0 = {acc[0] * inv, acc[1] * inv, acc[2] * inv, acc[3] * inv};
    float4 o1 = {acc[4] * inv, acc[5] * inv, acc[6] * inv, acc[7] * inv};
    ((float4*)dst)[0] = o0;
    ((float4*)dst)[1] = o1;
}

extern "C" void kernel_launch(void* const* d_in, const int* in_sizes, int n_in,
                              void* d_out, int out_size, void* d_ws, size_t ws_size,
                              hipStream_t stream)
{
    const float* x  = (const float*)d_in[0];
    const float* Wq = (const float*)d_in[1];
    const float* Wk = (const float*)d_in[2];
    const float* Wv = (const float*)d_in[3];
    float* out = (float*)d_out;

    // ws: qh | kh | vt (4 MiB each) | Wt (384 KiB)
    unsigned short* qh = (unsigned short*)d_ws;
    unsigned short* kh = qh + (size_t)BH * SEQ * DH;
    unsigned short* vt = kh + (size_t)BH * SEQ * DH;
    unsigned short* Wt = vt + (size_t)BH * SEQ * DH;

    prep_kernel<<<dim3(48), 256, 0, stream>>>(Wq, Wk, Wv, Wt);
    proj_kernel<<<dim3(512, 3), 256, 0, stream>>>(x, Wt, qh, kh, vt);
    attn_kernel<<<dim3(BH * (SEQ / QTILE)), 256, 0, stream>>>(qh, kh, vt, out);
}

// Round 16
// 135.575 us; speedup vs baseline: 2.8767x; 1.0789x over previous
//
#include <hip/hip_runtime.h>
#include <math.h>

#define BATCH 2
#define SEQ   4096
#define DIN   256
#define NH    8
#define DH    32            // head dim (dk = dv = 32)
#define BH    (BATCH*NH)    // 16
#define NSPLIT 4            // key-split factor
#define KRANGE (SEQ/NSPLIT) // 1024 keys per block
#define TILES  (KRANGE/64)  // 16 tiles of 64 keys
#define QTILE  256          // q rows per block; 64 per wave (4 subtiles of 16)

typedef short bf16x8 __attribute__((ext_vector_type(8)));
typedef float f32x4  __attribute__((ext_vector_type(4)));

// raw v_exp_f32 (base-2). Scores bounded -> no denorm fixup needed.
#if defined(__has_builtin)
#if __has_builtin(__builtin_amdgcn_exp2f)
#define EXP2(x) __builtin_amdgcn_exp2f(x)
#else
#define EXP2_ASM 1
#endif
#else
#define EXP2_ASM 1
#endif

// batch of 4 independent exp2: ONE trailing s_nop covers the trans-use hazard
__device__ __forceinline__ void exp4(float& a, float& b, float& c, float& d) {
#ifdef EXP2_ASM
    float r0, r1, r2, r3;
    asm("v_exp_f32 %0, %4\n\t"
        "v_exp_f32 %1, %5\n\t"
        "v_exp_f32 %2, %6\n\t"
        "v_exp_f32 %3, %7\n\t"
        "s_nop 1"
        : "=&v"(r0), "=&v"(r1), "=&v"(r2), "=&v"(r3)
        : "v"(a), "v"(b), "v"(c), "v"(d));
    a = r0; b = r1; c = r2; d = r3;
#else
    a = EXP2(a); b = EXP2(b); c = EXP2(c); d = EXP2(d);
#endif
}

#define SC2 0.25508218f     // log2(e)/sqrt(32) — folded into Q at projection

__device__ __forceinline__ unsigned short f2bf(float f) {
    unsigned int u = __builtin_bit_cast(unsigned int, f);
    u += 0x7fffu + ((u >> 16) & 1u);
    return (unsigned short)(u >> 16);
}

// pack 2 rounded bf16 (round-half-up), one v_perm + 2 adds
__device__ __forceinline__ unsigned int pack_bf2(float f0, float f1) {
    unsigned int u0 = __builtin_bit_cast(unsigned int, f0) + 0x8000u;
    unsigned int u1 = __builtin_bit_cast(unsigned int, f1) + 0x8000u;
    return __builtin_amdgcn_perm(u1, u0, 0x07060302u);
}

// pack 2 TRUNCATED bf16, single v_perm (hot attn loop). Truncation bias
// cancels exactly in softmax: l is computed from the same truncated P.
__device__ __forceinline__ unsigned int pack_bf2_t(float f0, float f1) {
    return __builtin_amdgcn_perm(__builtin_bit_cast(unsigned int, f1),
                                 __builtin_bit_cast(unsigned int, f0),
                                 0x07060302u);
}

#if defined(__has_builtin)
#if __has_builtin(__builtin_amdgcn_global_load_lds)
#define HAS_ASYNC_LDS 1
#endif
#endif

// async global->LDS, 16B/lane: wave-uniform LDS base, HW scatters lane i to
// base + i*16 (verified R5-R15).
__device__ __forceinline__ void stage16(const unsigned short* g,
                                        unsigned short* lds_base, int lane) {
#ifdef HAS_ASYNC_LDS
    __builtin_amdgcn_global_load_lds(
        (const __attribute__((address_space(1))) unsigned int*)g,
        (__attribute__((address_space(3))) unsigned int*)lds_base, 16, 0, 0);
#else
    *(bf16x8*)(lds_base + (size_t)lane * 8) = *(const bf16x8*)g;
#endif
}

// ---------------- prep: W -> Wt[t][k] bf16 (48 blocks) ----------------
__global__ __launch_bounds__(256) void prep_kernel(
    const float* __restrict__ Wq, const float* __restrict__ Wk, const float* __restrict__ Wv,
    unsigned short* __restrict__ Wt)
{
    __shared__ float ws[64][65];
    const int t = threadIdx.x;
    int wsel = blockIdx.x >> 4;
    int tile = blockIdx.x & 15;
    int tr = (tile >> 2) * 64;
    int tc = (tile & 3) * 64;
    const float* __restrict__ W = (wsel == 0) ? Wq : (wsel == 1) ? Wk : Wv;
    #pragma unroll
    for (int i = 0; i < 16; i++) {
        int row = i * 4 + (t >> 6), col = t & 63;
        ws[row][col] = W[(size_t)(tr + row) * DIN + tc + col];
    }
    __syncthreads();
    unsigned short* dst = Wt + (size_t)wsel * DIN * DIN;
    #pragma unroll
    for (int i = 0; i < 16; i++) {
        int orow = i * 4 + (t >> 6), ocol = t & 63;
        dst[(size_t)(tc + orow) * DIN + tr + ocol] = f2bf(ws[ocol][orow]);
    }
}

// ---------------- proj (R8-proven): x staged fp32->bf16 in-kernel ----------
__global__ __launch_bounds__(256) void proj_kernel(
    const float* __restrict__ x, const unsigned short* __restrict__ Wt,
    unsigned short* __restrict__ qh, unsigned short* __restrict__ kh,
    unsigned short* __restrict__ vt)
{
    __shared__ __align__(16) unsigned short abuf[8][4][64][8];  // 32 KiB
    __shared__ __align__(16) unsigned short bbuf[8][4][64][8];  // 32 KiB

    const int wsel = blockIdx.y;
    const int w    = threadIdx.x >> 6;
    const int lane = threadIdx.x & 63;
    const int quad = lane >> 4;
    const int l16  = lane & 15;

    const int sl   = lane ^ (lane >> 3);      // producer: lane -> slot
    const int sl16 = sl >> 2, squad = sl & 3;
    const int s_ = (l16 << 2) | quad;         // consumer slot for (l16, quad)
    const int jj = (s_ & 56) | ((s_ ^ (s_ >> 3)) & 7);

    int arow0, brow0;
    const unsigned short* Wbase;
    const float* Xbase;
    unsigned short (*wdst)[4][64][8];
    unsigned short (*xdst)[4][64][8];
    if (wsel < 2) {
        int tt = blockIdx.x >> 7, nt = blockIdx.x & 127;
        arow0 = tt * 64; brow0 = nt * 64;
        Wbase = Wt + (size_t)wsel * DIN * DIN + (size_t)arow0 * DIN;
        Xbase = x + (size_t)brow0 * DIN;
        wdst = abuf; xdst = bbuf;
    } else {
        int nt = blockIdx.x >> 2, tt = blockIdx.x & 3;
        arow0 = nt * 64; brow0 = tt * 64;
        Xbase = x + (size_t)arow0 * DIN;
        Wbase = Wt + (size_t)2 * DIN * DIN + (size_t)brow0 * DIN;
        wdst = bbuf; xdst = abuf;
    }

    #pragma unroll
    for (int i = 0; i < 8; i++) {
        int id = w * 8 + i;
        int kb = id >> 2, rt = id & 3;
        stage16(Wbase + (size_t)(rt * 16 + sl16) * DIN + kb * 32 + squad * 8,
                &wdst[kb][rt][0][0], lane);
    }
    #pragma unroll
    for (int i = 0; i < 8; i++) {
        int id = w * 8 + i;
        int kb = id >> 2, rt = id & 3;
        const float4* src = (const float4*)(Xbase + (size_t)(rt * 16 + sl16) * DIN
                                            + kb * 32 + squad * 8);
        float4 a = src[0], b = src[1];
        uint4 p = { pack_bf2(a.x, a.y), pack_bf2(a.z, a.w),
                    pack_bf2(b.x, b.y), pack_bf2(b.z, b.w) };
        *(uint4*)(&xdst[kb][rt][0][0] + (size_t)lane * 8) = p;
    }
    __syncthreads();

    f32x4 acc[4];
    #pragma unroll
    for (int c = 0; c < 4; c++) acc[c] = (f32x4){0.f, 0.f, 0.f, 0.f};
    #pragma unroll
    for (int kb = 0; kb < 8; kb++) {
        bf16x8 af = *(const bf16x8*)&abuf[kb][w][jj][0];
        #pragma unroll
        for (int c = 0; c < 4; c++) {
            bf16x8 bfr = *(const bf16x8*)&bbuf[kb][c][jj][0];
            acc[c] = __builtin_amdgcn_mfma_f32_16x16x32_bf16(af, bfr, acc[c], 0, 0, 0);
        }
    }

    if (wsel < 2) {
        const float scl = (wsel == 0) ? SC2 : 1.0f;
        unsigned short* __restrict__ dst0 = (wsel == 0) ? qh : kh;
        const int t0 = arow0 + w * 16;
        const int h = t0 >> 5, d0 = (t0 & 31) + quad * 4;
        #pragma unroll
        for (int c = 0; c < 4; c++) {
            int n = brow0 + c * 16 + l16;
            int b = n >> 12, n12 = n & 4095;
            unsigned int u01 = pack_bf2(acc[c][0] * scl, acc[c][1] * scl);
            unsigned int u23 = pack_bf2(acc[c][2] * scl, acc[c][3] * scl);
            *(uint2*)&dst0[((size_t)(b * NH + h) * SEQ + n12) * DH + d0] = make_uint2(u01, u23);
        }
    } else {
        const int n0w = arow0 + w * 16;
        const int b = n0w >> 12, nbase = (n0w & 4095) + quad * 4;
        #pragma unroll
        for (int c = 0; c < 4; c++) {
            int t = brow0 + c * 16;
            int h = t >> 5, d = (t & 31) + l16;
            unsigned int u01 = pack_bf2(acc[c][0], acc[c][1]);
            unsigned int u23 = pack_bf2(acc[c][2], acc[c][3]);
            *(uint2*)&vt[((size_t)(b * NH + h) * DH + d) * SEQ + nbase] = make_uint2(u01, u23);
        }
    }
}

// ---------------- Flash attention v16: R11 (best, 57.8us) + exp4 ------------
// Block = 256 q (64/wave, 4 waves) x 1024 keys. 2-barrier shared-tile loop:
// lowest per-unit instruction count of the 3 structures measured (R11 1083
// cyc/unit vs barrier-free 1414, fused 2900). 4 waves/SIMD is the register
// ceiling (o+lones = 48 acc VGPRs; caps <128 total spill — R12/R13).
// __launch_bounds__(256,4): total cap 128 = 64 arch + 64 acc, proven no-spill.
__global__ __launch_bounds__(256, 4) void attn_kernel(
    const unsigned short* __restrict__ qh,
    const unsigned short* __restrict__ kh,
    const unsigned short* __restrict__ vt,
    unsigned short* __restrict__ po, float* __restrict__ pl)
{
    __shared__ __align__(16) unsigned short pbuf[4][2][16][64];  // 16 KiB
    __shared__ __align__(16) unsigned short kbuf[2][4][64][8];   // 8 KiB
    __shared__ __align__(16) unsigned short vbuf[2][4][64][8];   // 8 KiB

    const int tid  = threadIdx.x;
    const int wave = tid >> 6;
    const int lane = tid & 63;
    const int quad = lane >> 4;
    const int l16  = lane & 15;
    const int sw   = l16 & 7;         // pbuf XOR swizzle key

    const int bh = blockIdx.x & 15;   // head -> XCD pinning
    const int qb = (blockIdx.x >> 4) & 15;
    const int ks = blockIdx.x >> 8;   // key-split 0..3
    const int q0 = qb * QTILE + wave * 64;
    const int kbase = ks * KRANGE;

    const unsigned short* __restrict__ Qp = qh + (size_t)bh * SEQ * DH;
    const unsigned short* __restrict__ Kp = kh + (size_t)bh * SEQ * DH;
    const unsigned short* __restrict__ Vp = vt + (size_t)bh * DH * SEQ;

    const int sl    = lane ^ (lane >> 3);
    const int sl16  = sl >> 2, squad = sl & 3;
    const unsigned short* ksrc = Kp + (size_t)(kbase + wave * 16 + sl16) * DH + squad * 8;
    const int vdh = wave >> 1, vkh = wave & 1;
    const unsigned short* vsrc = Vp + (size_t)(vdh * 16 + sl16) * SEQ + kbase + vkh * 32 + squad * 8;

    const int s_ = (l16 << 2) | quad;
    const int jj = (s_ & 56) | ((s_ ^ (s_ >> 3)) & 7);

    bf16x8 qf[4];
    #pragma unroll
    for (int i = 0; i < 4; i++)
        qf[i] = *(const bf16x8*)(Qp + (size_t)(q0 + i * 16 + l16) * DH + quad * 8);

    const bf16x8 ones = {0x3F80, 0x3F80, 0x3F80, 0x3F80,
                         0x3F80, 0x3F80, 0x3F80, 0x3F80};

    f32x4 o[4][2];
    f32x4 lones[4];
    #pragma unroll
    for (int i = 0; i < 4; i++) {
        o[i][0] = (f32x4){0.f, 0.f, 0.f, 0.f};
        o[i][1] = (f32x4){0.f, 0.f, 0.f, 0.f};
        lones[i] = (f32x4){0.f, 0.f, 0.f, 0.f};
    }
    const f32x4 z = {0.f, 0.f, 0.f, 0.f};

    stage16(ksrc, &kbuf[0][wave][0][0], lane);
    stage16(vsrc, &vbuf[0][wave][0][0], lane);
    ksrc += 64 * DH;
    vsrc += 64;

    for (int t = 0; t < TILES; t++) {
        const int buf = t & 1;

        __syncthreads();   // tile t staged; buf^1 free

        if (t + 1 < TILES) {
            stage16(ksrc, &kbuf[buf ^ 1][wave][0][0], lane);
            stage16(vsrc, &vbuf[buf ^ 1][wave][0][0], lane);
            ksrc += 64 * DH;
            vsrc += 64;
        }

        // read shared K/V fragments ONCE per wave, reuse across 4 q-subtiles
        bf16x8 kf[4], vf[4];
        #pragma unroll
        for (int c = 0; c < 4; c++) kf[c] = *(const bf16x8*)&kbuf[buf][c][jj][0];
        #pragma unroll
        for (int f = 0; f < 4; f++) vf[f] = *(const bf16x8*)&vbuf[buf][f][jj][0];

        #pragma unroll
        for (int qt = 0; qt < 4; qt++) {
            const int pr = qt & 1;    // pbuf parity region
            #pragma unroll
            for (int c = 0; c < 4; c++) {
                f32x4 s = __builtin_amdgcn_mfma_f32_16x16x32_bf16(kf[c], qf[qt], z, 0, 0, 0);
                float e0 = s[0], e1 = s[1], e2 = s[2], e3 = s[3];
                exp4(e0, e1, e2, e3);
                int chs = ((c * 2 + (quad >> 1)) ^ sw) * 8 + (quad & 1) * 4;
                *(uint2*)&pbuf[wave][pr][l16][chs] =
                    make_uint2(pack_bf2_t(e0, e1), pack_bf2_t(e2, e3));
            }
            bf16x8 pf0 = *(const bf16x8*)&pbuf[wave][pr][l16][((0 + quad) ^ sw) * 8];
            bf16x8 pf1 = *(const bf16x8*)&pbuf[wave][pr][l16][((4 + quad) ^ sw) * 8];
            o[qt][0] = __builtin_amdgcn_mfma_f32_16x16x32_bf16(pf0, vf[0], o[qt][0], 0, 0, 0);
            o[qt][0] = __builtin_amdgcn_mfma_f32_16x16x32_bf16(pf1, vf[1], o[qt][0], 0, 0, 0);
            o[qt][1] = __builtin_amdgcn_mfma_f32_16x16x32_bf16(pf0, vf[2], o[qt][1], 0, 0, 0);
            o[qt][1] = __builtin_amdgcn_mfma_f32_16x16x32_bf16(pf1, vf[3], o[qt][1], 0, 0, 0);
            lones[qt] = __builtin_amdgcn_mfma_f32_16x16x32_bf16(pf0, ones, lones[qt], 0, 0, 0);
            lones[qt] = __builtin_amdgcn_mfma_f32_16x16x32_bf16(pf1, ones, lones[qt], 0, 0, 0);
        }
    }

    // epilogue: bf16 partial O + fp32 partial l (lones rows align with o rows)
    const size_t obase = (size_t)(ks * BH + bh) * SEQ;
    #pragma unroll
    for (int qt = 0; qt < 4; qt++) {
        if (l16 == 0) {
            #pragma unroll
            for (int r = 0; r < 4; r++)
                pl[obase + q0 + qt * 16 + quad * 4 + r] = lones[qt][r];
        }
        #pragma unroll
        for (int r = 0; r < 4; r++) {
            int n = q0 + qt * 16 + quad * 4 + r;
            unsigned short* dst = po + (obase + n) * DH;
            dst[l16]      = f2bf(o[qt][0][r]);
            dst[16 + l16] = f2bf(o[qt][1][r]);
        }
    }
}

// ---------------- merge: sum bf16 split partials, divide, write out ---------
__global__ __launch_bounds__(256) void merge_kernel(
    const unsigned short* __restrict__ po, const float* __restrict__ pl,
    float* __restrict__ out)
{
    int t    = blockIdx.x * 256 + threadIdx.x;   // 0 .. 512K-1
    int d8   = t & 7;
    int pair = t >> 3;
    int bh   = pair >> 12;
    int n    = pair & 4095;
    float s0 = 0.f, s1 = 0.f, s2 = 0.f, s3 = 0.f, ls = 0.f;
    #pragma unroll
    for (int sp = 0; sp < NSPLIT; sp++) {
        size_t base = (size_t)(sp * BH + bh) * SEQ + n;
        uint2 v = ((const uint2*)(po + base * DH))[d8];
        s0 += __builtin_bit_cast(float, v.x << 16);
        s1 += __builtin_bit_cast(float, v.x & 0xFFFF0000u);
        s2 += __builtin_bit_cast(float, v.y << 16);
        s3 += __builtin_bit_cast(float, v.y & 0xFFFF0000u);
        ls += pl[base];
    }
    float inv = 1.f / ls;
    int b = bh >> 3, h = bh & 7;
    float4 o = {s0 * inv, s1 * inv, s2 * inv, s3 * inv};
    ((float4*)(out + ((size_t)b * SEQ + n) * (NH * DH) + h * DH))[d8] = o;
}

extern "C" void kernel_launch(void* const* d_in, const int* in_sizes, int n_in,
                              void* d_out, int out_size, void* d_ws, size_t ws_size,
                              hipStream_t stream)
{
    const float* x  = (const float*)d_in[0];
    const float* Wq = (const float*)d_in[1];
    const float* Wk = (const float*)d_in[2];
    const float* Wv = (const float*)d_in[3];
    float* out = (float*)d_out;

    // ws: qh|kh|vt (4 MiB each) | Wt (384 KiB) | po (16 MiB bf16) | pl (1 MiB f32)
    unsigned short* qh = (unsigned short*)d_ws;
    unsigned short* kh = qh + (size_t)BH * SEQ * DH;
    unsigned short* vt = kh + (size_t)BH * SEQ * DH;
    unsigned short* Wt = vt + (size_t)BH * SEQ * DH;
    unsigned short* po = Wt + 3 * DIN * DIN;
    float* pl = (float*)(po + (size_t)NSPLIT * BH * SEQ * DH);

    prep_kernel<<<dim3(48), 256, 0, stream>>>(Wq, Wk, Wv, Wt);
    proj_kernel<<<dim3(512, 3), 256, 0, stream>>>(x, Wt, qh, kh, vt);
    attn_kernel<<<dim3(BH * (SEQ / QTILE) * NSPLIT), 256, 0, stream>>>(qh, kh, vt, po, pl);
    merge_kernel<<<dim3(2048), 256, 0, stream>>>(po, pl, out);
}